// Round 1
// baseline (448.469 us; speedup 1.0000x reference)
//
#include <hip/hip_runtime.h>

#define TSTEPS 256
#define TT     32    // t-steps computed per block (8-row halo re-read: +25% of reads)
#define GROUP  8     // t-steps per pipelined load/compute batch

typedef float v4f __attribute__((ext_vector_type(4)));

__device__ __forceinline__ float4 f4mul(const float4 a, const float4 b) {
    return make_float4(a.x * b.x, a.y * b.y, a.z * b.z, a.w * b.w);
}
// 1 - a*b*m (b wave-uniform scalar) — NAND stage with delayed-n1 mask
__device__ __forceinline__ float4 f4nandm(const float4 a, const float b, const float4 m) {
    return make_float4(1.f - a.x * b * m.x, 1.f - a.y * b * m.y,
                       1.f - a.z * b * m.z, 1.f - a.w * b * m.w);
}

// cached load (halo rows are read twice -> let L2/LLC serve the re-read)
__device__ __forceinline__ float4 ld4(const float4* p) { return *p; }

// non-temporal store: write-once stream, don't allocate in L2/LLC
__device__ __forceinline__ void ntstore4(float4* p, const float4 v) {
    v4f t = {v.x, v.y, v.z, v.w};
    __builtin_nontemporal_store(t, (v4f*)p);
}

// tanhP1 is an 8-tap FIR, not an IIR: carried state is delayed x values and
// n1[t] = x[t]*x[t-4] (pure function of inputs) -> t-dimension parallelizes
// with an 8-row halo. 2D grid: x = column tiles, y = t tiles. 2048 blocks
// (~8/CU) give the TLP that the old 1-block/CU full-T sweep lacked.
__global__ __launch_bounds__(256) void tanhP1_kernel(
    const float* __restrict__ x,
    const float* __restrict__ c2, const float* __restrict__ c3,
    const float* __restrict__ c4, const float* __restrict__ c5,
    float* __restrict__ out, int N4)
{
    __shared__ float4 sbc[TT];
    const int tid = threadIdx.x;
    const int t0  = blockIdx.y * TT;
    if (tid < TT) {
        const int t = t0 + tid;
        sbc[tid] = make_float4(c2[t], c3[t], c4[t], c5[t]);
    }
    __syncthreads();

    const int j4 = blockIdx.x * blockDim.x + tid;   // float4 column index
    if (j4 >= N4) return;

    const float4* __restrict__ x4   = (const float4*)x + j4;
    float4* __restrict__       out4 = (float4*)out + j4;
    const size_t stride = (size_t)N4;

    // window state at loop entry t = t0:
    //   xd[k] = x[t0-1-k],  m[k] = n1[t0-1-k] = x[t0-1-k] * x[t0-5-k]
    float4 xd[8];
    float4 m[3];
    if (t0 == 0) {
        #pragma unroll
        for (int k = 0; k < 8; ++k) xd[k] = make_float4(0.f, 0.f, 0.f, 0.f);
        #pragma unroll
        for (int k = 0; k < 3; ++k) m[k] = make_float4(0.f, 0.f, 0.f, 0.f);
    } else {
        #pragma unroll
        for (int k = 0; k < 8; ++k)
            xd[k] = ld4(&x4[(size_t)(t0 - 1 - k) * stride]);
        m[0] = f4mul(xd[0], xd[4]);
        m[1] = f4mul(xd[1], xd[5]);
        m[2] = f4mul(xd[2], xd[6]);
    }

    // one group: consume 8 prefetched rows, store 8 output rows (nt)
    auto compute_group = [&](const float4 (&xt)[GROUP], int g) {
        #pragma unroll
        for (int i = 0; i < GROUP; ++i) {
            const float4 c  = sbc[g + i];
            const float4 n1 = f4mul(xt[i], xd[3]);                 // x[t] & x[t-4]
            const float4 n2 = make_float4(1.f - n1.x * c.x, 1.f - n1.y * c.x,
                                          1.f - n1.z * c.x, 1.f - n1.w * c.x);
            const float4 n3 = f4nandm(n2, c.y, m[0]);
            const float4 n4 = f4nandm(n3, c.z, m[1]);
            const float4 n5 = f4nandm(n4, c.w, m[2]);
            ntstore4(&out4[(size_t)(t0 + g + i) * stride], f4mul(n5, xd[7]));

            xd[7] = xd[6]; xd[6] = xd[5]; xd[5] = xd[4]; xd[4] = xd[3];
            xd[3] = xd[2]; xd[2] = xd[1]; xd[1] = xd[0]; xd[0] = xt[i];
            m[2] = m[1]; m[1] = m[0]; m[0] = n1;
        }
    };

    float4 bufA[GROUP], bufB[GROUP];

    // prime the pipeline: group 0 loads in flight
    #pragma unroll
    for (int i = 0; i < GROUP; ++i)
        bufA[i] = ld4(&x4[(size_t)(t0 + i) * stride]);

    #pragma unroll 1
    for (int g = 0; g < TT; g += 2 * GROUP) {
        // prefetch group g+1 while group g's loads complete / compute runs
        {
            const int tp = t0 + g + GROUP;           // < t0+TT, always valid
            #pragma unroll
            for (int i = 0; i < GROUP; ++i)
                bufB[i] = ld4(&x4[(size_t)(tp + i) * stride]);
        }
        compute_group(bufA, g);

        // prefetch group g+2 (skip past the end of this tile)
        if (g + 2 * GROUP < TT) {
            const int tp = t0 + g + 2 * GROUP;
            #pragma unroll
            for (int i = 0; i < GROUP; ++i)
                bufA[i] = ld4(&x4[(size_t)(tp + i) * stride]);
        }
        compute_group(bufB, g + GROUP);
    }
}

extern "C" void kernel_launch(void* const* d_in, const int* in_sizes, int n_in,
                              void* d_out, int out_size, void* d_ws, size_t ws_size,
                              hipStream_t stream) {
    const float* x  = (const float*)d_in[0];
    const float* c2 = (const float*)d_in[1];
    const float* c3 = (const float*)d_in[2];
    const float* c4 = (const float*)d_in[3];
    const float* c5 = (const float*)d_in[4];
    float* out = (float*)d_out;

    const int N  = in_sizes[0] / TSTEPS;  // 262144
    const int N4 = N / 4;                 // 65536 float4 columns

    dim3 block(256);
    dim3 grid(N4 / 256, TSTEPS / TT);     // 256 column-tiles x 8 t-tiles = 2048 blocks
    tanhP1_kernel<<<grid, block, 0, stream>>>(x, c2, c3, c4, c5, out, N4);
}

// Round 2
// 416.611 us; speedup vs baseline: 1.0765x; 1.0765x over previous
//
#include <hip/hip_runtime.h>

#define TSTEPS 256
#define GROUP  8     // t-steps per pipelined load/compute batch

typedef float v2f __attribute__((ext_vector_type(2)));

// non-temporal float2 load/store: every byte touched exactly once (zero-halo
// full-T sweep) -> bypass L2/LLC allocation for both streams
__device__ __forceinline__ float2 ntload2(const float2* p) {
    v2f v = __builtin_nontemporal_load((const v2f*)p);
    return make_float2(v.x, v.y);
}
__device__ __forceinline__ void ntstore2(float2* p, const float2 v) {
    v2f t = {v.x, v.y};
    __builtin_nontemporal_store(t, (v2f*)p);
}

// Zero-halo full-T sweep (round-0 structure: minimum 512 MiB traffic), but at
// float2 granularity: 131072 columns -> 2048 waves -> 2 waves/SIMD (vs 1 for
// float4). Same bytes, double the resident streams per SIMD so load/store
// issue stays continuous instead of bursty.
__global__ __launch_bounds__(256) void tanhP1_kernel(
    const float* __restrict__ x,
    const float* __restrict__ c2, const float* __restrict__ c3,
    const float* __restrict__ c4, const float* __restrict__ c5,
    float* __restrict__ out, int N2)
{
    // all 4 per-t constant bits in one float4 -> one broadcast ds_read_b128/step
    __shared__ float4 sbc[TSTEPS];
    const int tid = threadIdx.x;
    sbc[tid] = make_float4(c2[tid], c3[tid], c4[tid], c5[tid]);
    __syncthreads();

    const int j2 = blockIdx.x * blockDim.x + tid;   // float2 column index
    if (j2 >= N2) return;

    const float2* __restrict__ x2   = (const float2*)x + j2;
    float2* __restrict__       out2 = (float2*)out + j2;
    const size_t stride = (size_t)N2;

    // zero-initialized carry (t starts at 0 for every block)
    float2 xd[8];  // xd[k] = x[t-1-k]
    float2 m[3];   // m[k]  = n1[t-1-k]
    #pragma unroll
    for (int k = 0; k < 8; ++k) xd[k] = make_float2(0.f, 0.f);
    #pragma unroll
    for (int k = 0; k < 3; ++k) m[k] = make_float2(0.f, 0.f);

    // one group: consume 8 prefetched rows, store 8 output rows (nt)
    auto compute_group = [&](const float2 (&xt)[GROUP], int tg) {
        #pragma unroll
        for (int i = 0; i < GROUP; ++i) {
            const float4 c  = sbc[tg + i];
            const float2 n1 = make_float2(xt[i].x * xd[3].x, xt[i].y * xd[3].y);
            const float2 n2 = make_float2(1.f - n1.x * c.x, 1.f - n1.y * c.x);
            const float2 n3 = make_float2(1.f - n2.x * c.y * m[0].x,
                                          1.f - n2.y * c.y * m[0].y);
            const float2 n4 = make_float2(1.f - n3.x * c.z * m[1].x,
                                          1.f - n3.y * c.z * m[1].y);
            const float2 n5 = make_float2(1.f - n4.x * c.w * m[2].x,
                                          1.f - n4.y * c.w * m[2].y);
            ntstore2(&out2[(size_t)(tg + i) * stride],
                     make_float2(n5.x * xd[7].x, n5.y * xd[7].y));

            xd[7] = xd[6]; xd[6] = xd[5]; xd[5] = xd[4]; xd[4] = xd[3];
            xd[3] = xd[2]; xd[2] = xd[1]; xd[1] = xd[0]; xd[0] = xt[i];
            m[2] = m[1]; m[1] = m[0]; m[0] = n1;
        }
    };

    float2 bufA[GROUP], bufB[GROUP];

    // prime the pipeline: group 0 loads in flight
    #pragma unroll
    for (int i = 0; i < GROUP; ++i)
        bufA[i] = ntload2(&x2[(size_t)i * stride]);

    #pragma unroll 1
    for (int g = 0; g < TSTEPS; g += 2 * GROUP) {
        // prefetch group g+1 while group g's loads complete / compute runs
        {
            const int tp = g + GROUP;                // < TSTEPS, always valid
            #pragma unroll
            for (int i = 0; i < GROUP; ++i)
                bufB[i] = ntload2(&x2[(size_t)(tp + i) * stride]);
        }
        compute_group(bufA, g);

        // prefetch group g+2 (skip past the end)
        if (g + 2 * GROUP < TSTEPS) {
            const int tp = g + 2 * GROUP;
            #pragma unroll
            for (int i = 0; i < GROUP; ++i)
                bufA[i] = ntload2(&x2[(size_t)(tp + i) * stride]);
        }
        compute_group(bufB, g + GROUP);
    }
}

extern "C" void kernel_launch(void* const* d_in, const int* in_sizes, int n_in,
                              void* d_out, int out_size, void* d_ws, size_t ws_size,
                              hipStream_t stream) {
    const float* x  = (const float*)d_in[0];
    const float* c2 = (const float*)d_in[1];
    const float* c3 = (const float*)d_in[2];
    const float* c4 = (const float*)d_in[3];
    const float* c5 = (const float*)d_in[4];
    float* out = (float*)d_out;

    const int N  = in_sizes[0] / TSTEPS;  // 262144
    const int N2 = N / 2;                 // 131072 float2 columns

    dim3 block(256);
    dim3 grid(N2 / 256, 1);               // 512 blocks = 2/CU, zero-halo full-T sweep
    tanhP1_kernel<<<grid, block, 0, stream>>>(x, c2, c3, c4, c5, out, N2);
}